// Round 9
// baseline (54.089 us; speedup 1.0000x reference)
//
#include <hip/hip_runtime.h>
#include <math.h>

#define CROP 96
#define WIN 11
#define OUT 86          // CROP - WIN + 1
#define IMH 1080
#define IMW 1920
#define NIT 11          // chunks of 8 output rows: 86 = 10*8 + 6
#define RSW 356         // words per row-slot: 88*4 + 4 pad -> 4 mod 32 (bank-rotating)
#define NSLOT 32        // circular row buffer (power of 2)

typedef float v2f __attribute__((ext_vector_type(2)));

// LDS: hbuf[slot][x 0..87][4] = (P, Q, PP, QQ) — horizontal 11-tap conv of
// p=a+b, q=a-b, p^2, q^2 for input row `slot`, out-col x.

__global__ __launch_bounds__(256, 4) void ssim_kernel(
    const float* __restrict__ img,
    const float* __restrict__ imgr,
    const int* __restrict__ target,
    float* __restrict__ block_sums,
    unsigned int* __restrict__ counter,
    float* __restrict__ out,
    int nblk,
    float inv_npix)
{
    __shared__ __align__(16) float hbuf[NSLOT * RSW];   // 45568 B
    __shared__ float red[256];
    __shared__ unsigned int isLast;

    const int blk = blockIdx.x;          // 0 .. 3N-1
    const int s   = blk / 3;
    const int c   = blk % 3;

    const int xmin = target[s * 5 + 0];
    const int ymin = target[s * 5 + 1];

    const size_t cbase = (size_t)c * (IMH * IMW) + (size_t)ymin * IMW + (size_t)xmin;
    const float* __restrict__ pa = img  + cbase;
    const float* __restrict__ pb = imgr + cbase;

    const int tid = threadIdx.x;

    // gaussian weights (f32, matches reference)
    float gw[WIN];
    {
        float sum = 0.f;
        #pragma unroll
        for (int k = 0; k < WIN; ++k) {
            const float cc = (float)k - (float)(WIN - 1) * 0.5f;
            gw[k] = expf(-(cc * cc) / (2.0f * 1.5f * 1.5f));
            sum += gw[k];
        }
        const float inv = 1.0f / sum;
        #pragma unroll
        for (int k = 0; k < WIN; ++k) gw[k] *= inv;
    }

    // ---- horizontal 11-tap conv of one input row, 12 out-cols, packed pairs ----
    // All 44 global loads batched up-front into register arrays: one latency
    // epoch instead of ~4 interleaved load-use epochs (VGPR cap 128 via
    // __launch_bounds__(256,4) leaves room: ~44 window + 48 accum + misc).
    auto doA_task = [&](int row, int g) {
        const int xo = (g == 7) ? 74 : 12 * g;         // window xo..xo+21 <= 95
        const float* __restrict__ ra = pa + (size_t)row * IMW + xo;
        const float* __restrict__ rb = pb + (size_t)row * IMW + xo;

        float wa[22], wb[22];
        #pragma unroll
        for (int tt = 0; tt < 22; ++tt) wa[tt] = ra[tt];
        #pragma unroll
        for (int tt = 0; tt < 22; ++tt) wb[tt] = rb[tt];

        v2f aPQ[12] = {}; v2f aP2[12] = {};
        #pragma unroll
        for (int tt = 0; tt < 22; ++tt) {
            const v2f pq  = {wa[tt] + wb[tt], wa[tt] - wb[tt]};
            const v2f pq2 = pq * pq;
            #pragma unroll
            for (int jj = 0; jj < 12; ++jj) {
                const int kk = tt - jj;
                if (kk >= 0 && kk < WIN) {
                    aPQ[jj] += pq  * gw[kk];           // v_pk_fma_f32
                    aP2[jj] += pq2 * gw[kk];
                }
            }
        }
        const int sbase = (row & (NSLOT - 1)) * RSW;
        #pragma unroll
        for (int jj = 0; jj < 12; ++jj) {
            const int x = xo + jj;                     // g=7 overlaps g=6: bit-identical
            *(float4*)&hbuf[sbase + x * 4] =
                make_float4(aPQ[jj].x, aPQ[jj].y, aP2[jj].x, aP2[jj].y);
        }
    };

    // ---- prologue: fill input rows 0..17 (18 rows x 8 groups = 144 tasks) ----
    if (tid < 144) doA_task(tid >> 3, tid & 7);
    __syncthreads();

    const float C1 = 6.5025f;
    const float C2 = 58.5225f;
    float acc = 0.f;

    // hoisted per-thread task coordinates
    const int bx    = (tid < 172) ? (tid % 86) : 0;    // B: out-col
    const int bgrp  = (tid < 172) ? (tid / 86) : 0;    // B: 4-row group 0/1
    const int au    = tid - 192;                       // A: 0..63 when tid>=192
    const int arow0 = (au >> 3) + 18;
    const int ag    = au & 7;

    for (int k = 0; k < NIT; ++k) {
        const int r0out = 8 * k;

        if (tid < 172) {
            // ---- B: vertical 11-tap conv + SSIM, 4 out-rows x 1 col ----
            const int r0 = r0out + bgrp * 4;
            v2f mPQ[4] = {}; v2f mP2[4] = {};
            #pragma unroll
            for (int tt = 0; tt < 14; ++tt) {          // rows r0..r0+13 cover 4 out-rows
                const int slot = (r0 + tt) & (NSLOT - 1);
                const float4 f = *(const float4*)&hbuf[slot * RSW + bx * 4];
                const v2f fPQ = {f.x, f.y};
                const v2f fP2 = {f.z, f.w};
                #pragma unroll
                for (int jj = 0; jj < 4; ++jj) {
                    const int kk = tt - jj;
                    if (kk >= 0 && kk < WIN) {
                        mPQ[jj] += fPQ * gw[kk];       // v_pk_fma_f32
                        mP2[jj] += fP2 * gw[kk];
                    }
                }
            }
            #pragma unroll
            for (int jj = 0; jj < 4; ++jj) {
                if (r0 + jj < OUT) {
                    const v2f sq = mPQ[jj] * mPQ[jj];          // {P^2, Q^2}
                    const float mu12x2  = (sq.x - sq.y) * 0.5f;       // 2*mu1*mu2
                    const float musqsum = (sq.x + sq.y) * 0.5f;       // mu1^2+mu2^2
                    const float e_dif = (mP2[jj].x - mP2[jj].y) * 0.5f; // 2*E[ab]
                    const float e_sum = (mP2[jj].x + mP2[jj].y) * 0.5f; // E[a^2]+E[b^2]
                    const float s12x2 = e_dif - mu12x2;
                    const float ssum  = e_sum - musqsum;
                    const float num = (mu12x2 + C1) * (s12x2 + C2);
                    const float den = (musqsum + C1) * (ssum + C2);
                    acc += num * __builtin_amdgcn_rcpf(den);
                }
            }
        } else if (tid >= 192) {
            // ---- A: horizontal conv of next chunk's input rows ----
            const int row = r0out + arow0;             // 8k+18 .. 8k+25
            if (row < CROP) doA_task(row, ag);
        }
        __syncthreads();
    }

    // ---- deterministic block reduction ----
    red[tid] = acc;
    __syncthreads();
    #pragma unroll
    for (int off = 128; off > 0; off >>= 1) {
        if (tid < off) red[tid] += red[tid + off];
        __syncthreads();
    }

    // ---- fused finalize: last-arriving block reduces all block sums ----
    // Ticket pattern (no spin-waiting -> safe under any dispatch order).
    // Reduction order is fixed regardless of which block performs it, so the
    // output is bit-deterministic across replays.
    if (tid == 0) {
        block_sums[blk] = red[0];
        __threadfence();                               // release (device scope)
        const unsigned int t = atomicAdd(counter, 1u);
        isLast = (t == (unsigned int)(nblk - 1)) ? 1u : 0u;
    }
    __syncthreads();
    if (isLast) {
        __threadfence();                               // acquire (device scope)
        float ssum = 0.f;
        for (int i = tid; i < nblk; i += 256) ssum += block_sums[i];
        red[tid] = ssum;
        __syncthreads();
        #pragma unroll
        for (int off = 128; off > 0; off >>= 1) {
            if (tid < off) red[tid] += red[tid + off];
            __syncthreads();
        }
        if (tid == 0) out[0] = 5.0f * (1.0f - red[0] * inv_npix);
    }
}

extern "C" void kernel_launch(void* const* d_in, const int* in_sizes, int n_in,
                              void* d_out, int out_size, void* d_ws, size_t ws_size,
                              hipStream_t stream)
{
    const float* img  = (const float*)d_in[0];
    const float* imgr = (const float*)d_in[1];
    const int*   tgt  = (const int*)d_in[2];
    const int N = in_sizes[2] / 5;
    const int nblk = 3 * N;

    float*        block_sums = (float*)d_ws;
    unsigned int* counter    = (unsigned int*)((float*)d_ws + nblk);

    const float inv_npix = 1.0f / ((float)nblk * (float)(OUT * OUT));

    hipMemsetAsync((void*)counter, 0, sizeof(unsigned int), stream);
    ssim_kernel<<<nblk, 256, 0, stream>>>(img, imgr, tgt, block_sums, counter,
                                          (float*)d_out, nblk, inv_npix);
}